// Round 2
// baseline (201.017 us; speedup 1.0000x reference)
//
#include <hip/hip_runtime.h>
#include <hip/hip_bf16.h>

#define N_NODES 8192
#define F_IN 256
#define F_OUT 128

typedef __attribute__((ext_vector_type(4))) float f32x4;
typedef __attribute__((ext_vector_type(8))) short bf16x8;

static __device__ __forceinline__ short bfr(float x) {
    __hip_bfloat16 h = __float2bfloat16(x);   // RNE
    union { __hip_bfloat16 h; short s; } u; u.h = h;
    return u.s;
}

// Kernel 1: support^T[f][n] = sum_k X[n][k] * W[k][f]   (fp32 accum -> bf16 out)
// Block: 256 threads, 32 rows x 128 cols. Grid: 256.
__global__ __launch_bounds__(256) void support_kernel(
        const float* __restrict__ X, const float* __restrict__ W,
        unsigned short* __restrict__ supT) {
    __shared__ float Xs[32][68];
    __shared__ float Ws[64][128];
    const int t = threadIdx.x;
    const int n0 = blockIdx.x * 32;
    const int tc = t & 31;
    const int tr = t >> 5;
    float acc[4][4];
    #pragma unroll
    for (int i = 0; i < 4; ++i)
        #pragma unroll
        for (int j = 0; j < 4; ++j) acc[i][j] = 0.f;

    for (int k0 = 0; k0 < F_IN; k0 += 64) {
        __syncthreads();
        {
            const int r = t >> 3, kc = (t & 7) * 8;
            const float* src = X + (size_t)(n0 + r) * F_IN + k0 + kc;
            f32x4 v0 = *(const f32x4*)src;
            f32x4 v1 = *(const f32x4*)(src + 4);
            *(f32x4*)&Xs[r][kc]     = v0;
            *(f32x4*)&Xs[r][kc + 4] = v1;
        }
        {
            const int col = t & 127, kb = t >> 7;
            #pragma unroll
            for (int i = 0; i < 32; ++i) {
                const int k = kb + i * 2;
                Ws[k][col] = W[(size_t)(k0 + k) * F_OUT + col];
            }
        }
        __syncthreads();
        #pragma unroll 8
        for (int k = 0; k < 64; ++k) {
            const f32x4 b = *(const f32x4*)&Ws[k][tc * 4];
            float a[4];
            #pragma unroll
            for (int i = 0; i < 4; ++i) a[i] = Xs[tr * 4 + i][k];
            #pragma unroll
            for (int i = 0; i < 4; ++i) {
                acc[i][0] += a[i] * b.x; acc[i][1] += a[i] * b.y;
                acc[i][2] += a[i] * b.z; acc[i][3] += a[i] * b.w;
            }
        }
    }
    #pragma unroll
    for (int j = 0; j < 4; ++j) {
        const int col = tc * 4 + j;
        #pragma unroll
        for (int i = 0; i < 4; ++i) {
            supT[(size_t)col * N_NODES + n0 + tr * 4 + i] = (unsigned short)bfr(acc[i][j]);
        }
    }
}

// Kernel 2: out = adj @ support + bias. No LDS, no barriers.
// Grid 512 blocks x 128 thr (2 waves). Block = 16-row stripe; wave w = 64 cols.
// MFMA fragments loaded directly from global: A from adj (fp32->bf16 in-reg,
// HBM stream), B from supT (bf16, 2MB -> L2-resident). 4-deep SW pipeline.
__global__ __launch_bounds__(128) void gcn_kernel(
        const float* __restrict__ adj, const unsigned short* __restrict__ supT,
        const float* __restrict__ bias, float* __restrict__ out) {
    const int l = threadIdx.x & 63;
    const int w = threadIdx.x >> 6;                 // 0..1
    const int n0 = blockIdx.x * 16;
    const int arow = l & 15;
    const int koff = (l >> 4) * 8;                  // k sub-offset within 32-step

    const float* aptr = adj + (size_t)(n0 + arow) * N_NODES + koff;
    const unsigned short* bptr =
        supT + (size_t)(w * 64 + (l & 15)) * N_NODES + koff;

    f32x4 acc0 = {0.f,0.f,0.f,0.f}, acc1 = {0.f,0.f,0.f,0.f};
    f32x4 acc2 = {0.f,0.f,0.f,0.f}, acc3 = {0.f,0.f,0.f,0.f};

    // 4 named pipeline stages (no runtime indexing -> stays in VGPRs)
    f32x4 a0S0, a1S0, a0S1, a1S1, a0S2, a1S2, a0S3, a1S3;
    bf16x8 b0S0, b1S0, b2S0, b3S0;
    bf16x8 b0S1, b1S1, b2S1, b3S1;
    bf16x8 b0S2, b1S2, b2S2, b3S2;
    bf16x8 b0S3, b1S3, b2S3, b3S3;

#define LOADA(S, KB) { \
    a0##S = *(const f32x4*)(aptr + (KB)); \
    a1##S = *(const f32x4*)(aptr + (KB) + 4); }
#define LOADB(S, KB) { \
    b0##S = *(const bf16x8*)(bptr + (KB)); \
    b1##S = *(const bf16x8*)(bptr + (KB) + 16 * (size_t)N_NODES); \
    b2##S = *(const bf16x8*)(bptr + (KB) + 32 * (size_t)N_NODES); \
    b3##S = *(const bf16x8*)(bptr + (KB) + 48 * (size_t)N_NODES); }
#define SUB(S, KNEXT) { \
    bf16x8 af; \
    af[0] = bfr(a0##S.x); af[1] = bfr(a0##S.y); \
    af[2] = bfr(a0##S.z); af[3] = bfr(a0##S.w); \
    af[4] = bfr(a1##S.x); af[5] = bfr(a1##S.y); \
    af[6] = bfr(a1##S.z); af[7] = bfr(a1##S.w); \
    LOADA(S, KNEXT); \
    acc0 = __builtin_amdgcn_mfma_f32_16x16x32_bf16(af, b0##S, acc0, 0, 0, 0); \
    acc1 = __builtin_amdgcn_mfma_f32_16x16x32_bf16(af, b1##S, acc1, 0, 0, 0); \
    acc2 = __builtin_amdgcn_mfma_f32_16x16x32_bf16(af, b2##S, acc2, 0, 0, 0); \
    acc3 = __builtin_amdgcn_mfma_f32_16x16x32_bf16(af, b3##S, acc3, 0, 0, 0); \
    LOADB(S, KNEXT); }

    LOADA(S0, 0);      LOADB(S0, 0);
    LOADA(S1, 32);     LOADB(S1, 32);
    LOADA(S2, 64);     LOADB(S2, 64);
    LOADA(S3, 96);     LOADB(S3, 96);

    for (int kk = 0; kk < 256; kk += 4) {
        SUB(S0, ((kk + 4) & 255) * 32);
        SUB(S1, ((kk + 5) & 255) * 32);
        SUB(S2, ((kk + 6) & 255) * 32);
        SUB(S3, ((kk + 7) & 255) * 32);
    }
#undef LOADA
#undef LOADB
#undef SUB

    // epilogue: C/D layout col = l&15, row = (l>>4)*4 + i  [m89-verified]
    const int col0 = w * 64 + (l & 15);
    const int r0 = n0 + (l >> 4) * 4;
    const float bv0 = bias[col0];
    const float bv1 = bias[col0 + 16];
    const float bv2 = bias[col0 + 32];
    const float bv3 = bias[col0 + 48];
    #pragma unroll
    for (int i = 0; i < 4; ++i) {
        float* o = out + (size_t)(r0 + i) * F_OUT + col0;
        o[0]  = acc0[i] + bv0;
        o[16] = acc1[i] + bv1;
        o[32] = acc2[i] + bv2;
        o[48] = acc3[i] + bv3;
    }
}

extern "C" void kernel_launch(void* const* d_in, const int* in_sizes, int n_in,
                              void* d_out, int out_size, void* d_ws, size_t ws_size,
                              hipStream_t stream) {
    const float* input  = (const float*)d_in[0];
    const float* adj    = (const float*)d_in[1];
    const float* weight = (const float*)d_in[2];
    const float* bias   = (const float*)d_in[3];
    float* out = (float*)d_out;
    unsigned short* supT = (unsigned short*)d_ws;   // [F_OUT][N_NODES] bf16 = 2 MiB

    support_kernel<<<N_NODES / 32, 256, 0, stream>>>(input, weight, supT);
    gcn_kernel<<<N_NODES / 16, 128, 0, stream>>>(adj, supT, bias, out);
}

// Round 3
// 99.816 us; speedup vs baseline: 2.0139x; 2.0139x over previous
//
#include <hip/hip_runtime.h>
#include <hip/hip_bf16.h>

#define N_NODES 8192
#define F_IN 256
#define F_OUT 128

typedef __attribute__((ext_vector_type(4))) float f32x4;
typedef __attribute__((ext_vector_type(8))) short bf16x8;

static __device__ __forceinline__ short bfr(float x) {
    __hip_bfloat16 h = __float2bfloat16(x);   // RNE
    union { __hip_bfloat16 h; short s; } u; u.h = h;
    return u.s;
}

static __device__ __forceinline__ void gload16(const void* g, void* l) {
    __builtin_amdgcn_global_load_lds(
        (const __attribute__((address_space(1))) unsigned int*)g,
        (__attribute__((address_space(3))) unsigned int*)l, 16, 0, 0);
}

// Kernel 1: support^T[f][n] = sum_k X[n][k] * W[k][f]   (fp32 accum -> bf16 out)
__global__ __launch_bounds__(256) void support_kernel(
        const float* __restrict__ X, const float* __restrict__ W,
        unsigned short* __restrict__ supT) {
    __shared__ float Xs[32][68];
    __shared__ float Ws[64][128];
    const int t = threadIdx.x;
    const int n0 = blockIdx.x * 32;
    const int tc = t & 31;
    const int tr = t >> 5;
    float acc[4][4];
    #pragma unroll
    for (int i = 0; i < 4; ++i)
        #pragma unroll
        for (int j = 0; j < 4; ++j) acc[i][j] = 0.f;

    for (int k0 = 0; k0 < F_IN; k0 += 64) {
        __syncthreads();
        {
            const int r = t >> 3, kc = (t & 7) * 8;
            const float* src = X + (size_t)(n0 + r) * F_IN + k0 + kc;
            f32x4 v0 = *(const f32x4*)src;
            f32x4 v1 = *(const f32x4*)(src + 4);
            *(f32x4*)&Xs[r][kc]     = v0;
            *(f32x4*)&Xs[r][kc + 4] = v1;
        }
        {
            const int col = t & 127, kb = t >> 7;
            #pragma unroll
            for (int i = 0; i < 32; ++i) {
                const int k = kb + i * 2;
                Ws[k][col] = W[(size_t)(k0 + k) * F_OUT + col];
            }
        }
        __syncthreads();
        #pragma unroll 8
        for (int k = 0; k < 64; ++k) {
            const f32x4 b = *(const f32x4*)&Ws[k][tc * 4];
            float a[4];
            #pragma unroll
            for (int i = 0; i < 4; ++i) a[i] = Xs[tr * 4 + i][k];
            #pragma unroll
            for (int i = 0; i < 4; ++i) {
                acc[i][0] += a[i] * b.x; acc[i][1] += a[i] * b.y;
                acc[i][2] += a[i] * b.z; acc[i][3] += a[i] * b.w;
            }
        }
    }
    #pragma unroll
    for (int j = 0; j < 4; ++j) {
        const int col = tc * 4 + j;
        #pragma unroll
        for (int i = 0; i < 4; ++i) {
            supT[(size_t)col * N_NODES + n0 + tr * 4 + i] =
                (unsigned short)bfr(acc[i][j]);
        }
    }
}

// Kernel 2: out = adj @ support + bias.
// BM=16, BK=64, 512 blocks x 256 thr (4 waves, wave w -> cols w*32..w*32+31).
// Triple-buffered LDS, all staging via global_load_lds with pre-swizzled
// global source (XOR chunk^row -> conflict-free ds_read), counted vmcnt,
// raw s_barrier (no vmcnt(0) drain in the main loop).
#define BK 64
#define NT (N_NODES / BK)      // 128
#define BUFB 20480             // 4KB A (fp32 16x64) + 16KB B (bf16 128x64)

__global__ __launch_bounds__(256) void gcn_kernel(
        const float* __restrict__ adj, const unsigned short* __restrict__ supT,
        const float* __restrict__ bias, float* __restrict__ out) {
    __shared__ char lds[3 * BUFB];
    const int t = threadIdx.x;
    const int l = t & 63;
    const int w = t >> 6;                  // 0..3
    const int n0 = blockIdx.x * 16;

    // ---- staging source pointers (per-lane, pre-swizzled) ----
    // A: dest chunk (row s_ar = 4w + l>>4, cd = l&15) <- src chunk cd ^ s_ar
    const int s_ar = 4 * w + (l >> 4);
    const char* gA = (const char*)adj
        + (size_t)(n0 + s_ar) * (N_NODES * 4)
        + (((l & 15) ^ (s_ar & 15)) * 16);
    // B: instr j covers f = 32w + 8j + (l>>3); f&7 == l>>3.
    //    dest chunk (f, cd = l&7) <- src chunk cd ^ (f&7)
    const char* gB = (const char*)supT
        + (size_t)(32 * w + (l >> 3)) * (N_NODES * 2)
        + (((l & 7) ^ (l >> 3)) * 16);
    const size_t bstep = (size_t)8 * N_NODES * 2;   // 8 supT rows = 131072 B

    // LDS dest region offsets (wave-uniform)
    const int adst = w * 1024;                      // A: rows 4w..4w+3
    const int bdst = 4096 + w * 4096;               // B: f rows 32w..32w+31

    // ---- read-side offsets ----
    const int a_row_off = (l & 15) * 256;           // A row byte offset
    const int a_key = l & 15;                       // A swizzle key
    const int b_row_off = 4096 + (w * 32 + (l & 15)) * 128;
    const int b_key = l & 7;                        // B swizzle key (f&7)
    const int cA2 = (l >> 4) * 2;
    const int cB1 = l >> 4;

    f32x4 acc0 = {0.f, 0.f, 0.f, 0.f};
    f32x4 acc1 = {0.f, 0.f, 0.f, 0.f};

    // ---- prologue: stage tiles 0,1 into buffers 0,1 (5 loads/wave each)
    #pragma unroll
    for (int pt = 0; pt < 2; ++pt) {
        char* buf = &lds[pt * BUFB];
        gload16(gA + (size_t)pt * 256, buf + adst);
        const char* bs = gB + (size_t)pt * 128;
        gload16(bs,             buf + bdst);
        gload16(bs + bstep,     buf + bdst + 1024);
        gload16(bs + 2 * bstep, buf + bdst + 2048);
        gload16(bs + 3 * bstep, buf + bdst + 3072);
    }

    int bcur = 0;
    for (int tt = 0; tt < NT; ++tt) {
        // ensure tile tt's staging landed; keep tile tt+1's 5 loads in flight
        if (tt < NT - 1) asm volatile("s_waitcnt vmcnt(5)" ::: "memory");
        else             asm volatile("s_waitcnt vmcnt(0)" ::: "memory");
        __builtin_amdgcn_s_barrier();
        asm volatile("" ::: "memory");

        // issue staging for tile tt+2 (buffer freed by the barrier above)
        if (tt + 2 < NT) {
            int b2 = bcur + 2; if (b2 >= 3) b2 -= 3;
            char* buf = &lds[b2 * BUFB];
            const size_t kt = (size_t)(tt + 2);
            gload16(gA + kt * 256, buf + adst);
            const char* bs = gB + kt * 128;
            gload16(bs,             buf + bdst);
            gload16(bs + bstep,     buf + bdst + 1024);
            gload16(bs + 2 * bstep, buf + bdst + 2048);
            gload16(bs + 3 * bstep, buf + bdst + 3072);
        }

        // compute tile tt from buffer bcur
        const char* buf = &lds[bcur * BUFB];
        #pragma unroll
        for (int ks = 0; ks < 2; ++ks) {
            const int ca = ks * 8 + cA2;
            f32x4 alo = *(const f32x4*)(buf + a_row_off + (((ca    ) ^ a_key) * 16));
            f32x4 ahi = *(const f32x4*)(buf + a_row_off + (((ca + 1) ^ a_key) * 16));
            bf16x8 af;
            af[0] = bfr(alo.x); af[1] = bfr(alo.y);
            af[2] = bfr(alo.z); af[3] = bfr(alo.w);
            af[4] = bfr(ahi.x); af[5] = bfr(ahi.y);
            af[6] = bfr(ahi.z); af[7] = bfr(ahi.w);
            const int cb = ks * 4 + cB1;
            bf16x8 b0 = *(const bf16x8*)(buf + b_row_off        + ((cb ^ b_key) * 16));
            bf16x8 b1 = *(const bf16x8*)(buf + b_row_off + 2048 + ((cb ^ b_key) * 16));
            acc0 = __builtin_amdgcn_mfma_f32_16x16x32_bf16(af, b0, acc0, 0, 0, 0);
            acc1 = __builtin_amdgcn_mfma_f32_16x16x32_bf16(af, b1, acc1, 0, 0, 0);
        }
        ++bcur; if (bcur == 3) bcur = 0;
    }

    // epilogue: C/D layout col = l&15 (N dim), row = (l>>4)*4 + i (M dim)
    const int col = w * 32 + (l & 15);
    const int row0 = n0 + (l >> 4) * 4;
    const float bv0 = bias[col];
    const float bv1 = bias[col + 16];
    #pragma unroll
    for (int i = 0; i < 4; ++i) {
        float* o = out + (size_t)(row0 + i) * F_OUT + col;
        o[0]  = acc0[i] + bv0;
        o[16] = acc1[i] + bv1;
    }
}

extern "C" void kernel_launch(void* const* d_in, const int* in_sizes, int n_in,
                              void* d_out, int out_size, void* d_ws, size_t ws_size,
                              hipStream_t stream) {
    const float* input  = (const float*)d_in[0];
    const float* adj    = (const float*)d_in[1];
    const float* weight = (const float*)d_in[2];
    const float* bias   = (const float*)d_in[3];
    float* out = (float*)d_out;
    unsigned short* supT = (unsigned short*)d_ws;   // [F_OUT][N_NODES] bf16 = 2 MiB

    support_kernel<<<N_NODES / 32, 256, 0, stream>>>(input, weight, supT);
    gcn_kernel<<<N_NODES / 16, 256, 0, stream>>>(adj, supT, bias, out);
}